// Round 2
// baseline (1528.480 us; speedup 1.0000x reference)
//
#include <hip/hip_runtime.h>
#include <stdint.h>

typedef __attribute__((ext_vector_type(4))) float f32x4;
typedef __attribute__((ext_vector_type(8))) short bf16x8;
typedef __attribute__((ext_vector_type(8))) unsigned short u16x8;
typedef __attribute__((ext_vector_type(4))) unsigned short u16x4;

#define B_ 4
#define L_ 18
#define T_ 512
#define D_ 2048
#define DD_ 512
#define OUT_ 1024
#define H_ 8
#define BL_ 72

// ws layout (bytes)
#define WEFF_OFF 0
#define KP_OFF   201326592
#define VP_OFF   276824064
#define QP_OFF   352321536
#define POOL_OFF 352468992

__device__ __forceinline__ unsigned short f2bf(float f) {
  unsigned int u = __float_as_uint(f);
  u += 0x7FFFu + ((u >> 16) & 1u);
  return (unsigned short)(u >> 16);
}
__device__ __forceinline__ float bf2f(unsigned short h) {
  return __uint_as_float(((unsigned int)h) << 16);
}
__device__ __forceinline__ int get_nb(const float* gate, int b) {
  int nb = 0;
#pragma unroll
  for (int n = 0; n < 8; ++n) nb = (gate[b * 8 + n] > 0.5f) ? n : nb;
  return nb;
}

// ---------------------------------------------------------------------------
// Build W_eff = W[g] + B[g,nb] @ A[g,nb], stored transposed [o][d] as bf16
// hi/lo planes, pre-tiled (128-o x 64-d blocks) and pre-XOR-swizzled so the
// GEMM can global_load_lds it linearly.
// grid: [tau][b][g][nt][kstep] = 2*4*6*4*32 = 6144
// ---------------------------------------------------------------------------
__global__ __launch_bounds__(256)
void build_weff(const float* __restrict__ Wk, const float* __restrict__ Ak,
                const float* __restrict__ Bk, const float* __restrict__ Wv,
                const float* __restrict__ Av, const float* __restrict__ Bv,
                const float* __restrict__ gate, unsigned short* __restrict__ weff) {
  int bid = blockIdx.x;
  int kstep = bid & 31; bid >>= 5;
  int nt = bid & 3; bid >>= 2;
  int g = bid % 6; bid /= 6;
  int b = bid & 3; bid >>= 2;
  int tau = bid;
  int nb = get_nb(gate, b);
  const float* Wsrc = (tau ? Wv : Wk) + (size_t)g * D_ * DD_;
  const float* Asrc = (tau ? Av : Ak) + ((size_t)(g * 8 + nb) * 16) * D_;
  const float* Bsrc = (tau ? Bv : Bk) + (size_t)(g * 8 + nb) * DD_ * 16;
  __shared__ float W_s[64][132];
  __shared__ float A_s[16][64];
  __shared__ float B_s[128][17];
  int tid = threadIdx.x;
  for (int idx = tid; idx < 8192; idx += 256) {
    int dl = idx >> 7, ol = idx & 127;
    W_s[dl][ol] = Wsrc[(size_t)(kstep * 64 + dl) * DD_ + nt * 128 + ol];
  }
  for (int idx = tid; idx < 1024; idx += 256) {
    int rr = idx >> 6, dl = idx & 63;
    A_s[rr][dl] = Asrc[rr * D_ + kstep * 64 + dl];
  }
  for (int idx = tid; idx < 2048; idx += 256) {
    int ol = idx >> 4, rr = idx & 15;
    B_s[ol][rr] = Bsrc[(nt * 128 + ol) * 16 + rr];
  }
  __syncthreads();
  unsigned short* outhi = weff + (size_t)((tau * 24 + b * 6 + g) * 2) * 1048576
                          + nt * 262144 + kstep * 8192;
  unsigned short* outlo = outhi + 1048576;
  int row = tid >> 1;
  int sw = (row & 7) << 3;
#pragma unroll
  for (int grp = 0; grp < 4; ++grp) {
    int kk0 = (tid & 1) * 32 + grp * 8;
    u16x8 hv, lv;
#pragma unroll
    for (int j = 0; j < 8; ++j) {
      int k = (kk0 + j) ^ sw;
      float v = W_s[k][row];
#pragma unroll
      for (int r = 0; r < 16; ++r) v = fmaf(B_s[row][r], A_s[r][k], v);
      unsigned short h = f2bf(v);
      hv[j] = h;
      lv[j] = f2bf(v - bf2f(h));
    }
    *(u16x8*)(outhi + row * 64 + kk0) = hv;
    *(u16x8*)(outlo + row * 64 + kk0) = lv;
  }
}

// ---------------------------------------------------------------------------
// Qp (nq=1) in fp32: per (b,l) matrix-vector + LoRA. grid = 72 blocks.
// ---------------------------------------------------------------------------
__global__ __launch_bounds__(256)
void qp_kernel(const float* __restrict__ qparams, const float* __restrict__ Wq,
               const float* __restrict__ bq, const float* __restrict__ Aq,
               const float* __restrict__ Bq, const float* __restrict__ gate,
               float* __restrict__ Qp) {
  int bl = blockIdx.x;
  int b = bl / 18, l = bl % 18, g = l / 3;
  int nb = get_nb(gate, b);
  int tid = threadIdx.x;
  __shared__ float x_s[2048];
  __shared__ float axp[256][17];
  __shared__ float ax[16];
  const float* x = qparams + (size_t)l * D_;
  for (int i = tid; i < 2048; i += 256) x_s[i] = x[i];
  const float* A = Aq + ((size_t)(g * 8 + nb) * 16) * D_;
  __syncthreads();
  float pa[16];
#pragma unroll
  for (int r = 0; r < 16; ++r) pa[r] = 0.f;
  for (int d0 = 0; d0 < 2048; d0 += 256) {
    float xv = x_s[d0 + tid];
#pragma unroll
    for (int r = 0; r < 16; ++r) pa[r] = fmaf(xv, A[r * D_ + d0 + tid], pa[r]);
  }
#pragma unroll
  for (int r = 0; r < 16; ++r) axp[tid][r] = pa[r];
  __syncthreads();
  if (tid < 16) {
    float s = 0.f;
    for (int i = 0; i < 256; ++i) s += axp[i][tid];
    ax[tid] = s;
  }
  __syncthreads();
  const float* W = Wq + (size_t)g * D_ * DD_;
  const float* Bm = Bq + (size_t)(g * 8 + nb) * DD_ * 16;
  float a0 = bq[g * DD_ + tid];
  float a1 = bq[g * DD_ + tid + 256];
  for (int d = 0; d < 2048; ++d) {
    float xv = x_s[d];
    a0 = fmaf(xv, W[(size_t)d * DD_ + tid], a0);
    a1 = fmaf(xv, W[(size_t)d * DD_ + tid + 256], a1);
  }
#pragma unroll
  for (int r = 0; r < 16; ++r) {
    a0 = fmaf(ax[r], Bm[tid * 16 + r], a0);
    a1 = fmaf(ax[r], Bm[(tid + 256) * 16 + r], a1);
  }
  Qp[(size_t)bl * DD_ + tid] = a0;
  Qp[(size_t)bl * DD_ + tid + 256] = a1;
}

// ---------------------------------------------------------------------------
// Main GEMM: Out[b,l] = X[b,l] @ W_eff (3-term bf16-split MFMA, fp32 acc)
// 128x128 tile, BK=64, 4 waves, 16x16x32 MFMA.
// grid: [tau][b][l][mt][nt] = 2*4*18*4*4 = 2304
// ---------------------------------------------------------------------------
__global__ __launch_bounds__(256, 2)
void gemm_kv(const float* __restrict__ Kin, const float* __restrict__ Vin,
             const unsigned short* __restrict__ weff,
             const float* __restrict__ bk, const float* __restrict__ bv,
             const float* __restrict__ gate,
             float* __restrict__ Kp, float* __restrict__ Vp) {
  int bid = blockIdx.x;
  int nt = bid & 3; bid >>= 2;
  int mt = bid & 3; bid >>= 2;
  int l = bid % 18; bid /= 18;
  int b = bid & 3; bid >>= 2;
  int tau = bid;
  int g = l / 3;
  int bl = b * 18 + l;

  __shared__ char smem[65536];
  char* Xhi = smem;
  char* Xlo = smem + 16384;
  char* Whi = smem + 32768;
  char* Wlo = smem + 49152;

  int tid = threadIdx.x;
  int lane = tid & 63;
  int wv = tid >> 6;
  int wm = wv >> 1, wn = wv & 1;

  const float* X = (tau ? Vin : Kin) + (size_t)bl * T_ * D_ + (size_t)mt * 128 * D_;
  const unsigned short* wb = weff + (size_t)((tau * 24 + b * 6 + g) * 2) * 1048576
                             + nt * 262144;

  f32x4 acc[4][4];
#pragma unroll
  for (int m = 0; m < 4; ++m)
#pragma unroll
    for (int n = 0; n < 4; ++n) acc[m][n] = (f32x4){0.f, 0.f, 0.f, 0.f};

  for (int kstep = 0; kstep < 32; ++kstep) {
    __syncthreads();
    // W_eff staging: linear global_load_lds (layout pre-swizzled in global)
#pragma unroll
    for (int j = 0; j < 4; ++j) {
      int c = wv * 4 + j;
      const unsigned short* gh = wb + kstep * 8192 + c * 512 + lane * 8;
      __builtin_amdgcn_global_load_lds(
          (const __attribute__((address_space(1))) unsigned int*)gh,
          (__attribute__((address_space(3))) unsigned int*)(Whi + c * 1024), 16, 0, 0);
      const unsigned short* gl = gh + 1048576;
      __builtin_amdgcn_global_load_lds(
          (const __attribute__((address_space(1))) unsigned int*)gl,
          (__attribute__((address_space(3))) unsigned int*)(Wlo + c * 1024), 16, 0, 0);
    }
    // X staging: fp32 -> bf16 hi/lo, swizzled ds_write
#pragma unroll
    for (int i = 0; i < 8; ++i) {
      int idx = i * 256 + tid;
      int row = idx >> 4;
      int c4 = idx & 15;
      const f32x4 xv = *(const f32x4*)(X + (size_t)row * D_ + kstep * 64 + c4 * 4);
      u16x4 h4, l4;
#pragma unroll
      for (int q = 0; q < 4; ++q) {
        unsigned short h = f2bf(xv[q]);
        h4[q] = h;
        l4[q] = f2bf(xv[q] - bf2f(h));
      }
      int off = row * 128 + ((c4 * 8) ^ ((row & 7) << 4));
      *(u16x4*)(Xhi + off) = h4;
      *(u16x4*)(Xlo + off) = l4;
    }
    __syncthreads();
#pragma unroll
    for (int ks = 0; ks < 2; ++ks) {
      bf16x8 ah[4], al[4], bh[4], blo[4];
#pragma unroll
      for (int m = 0; m < 4; ++m) {
        int r = wm * 64 + m * 16 + (lane & 15);
        int off = r * 128 + ((ks * 64 + (lane >> 4) * 16) ^ ((r & 7) << 4));
        ah[m] = *(const bf16x8*)(Xhi + off);
        al[m] = *(const bf16x8*)(Xlo + off);
      }
#pragma unroll
      for (int n = 0; n < 4; ++n) {
        int r = wn * 64 + n * 16 + (lane & 15);
        int off = r * 128 + ((ks * 64 + (lane >> 4) * 16) ^ ((r & 7) << 4));
        bh[n] = *(const bf16x8*)(Whi + off);
        blo[n] = *(const bf16x8*)(Wlo + off);
      }
#pragma unroll
      for (int m = 0; m < 4; ++m)
#pragma unroll
        for (int n = 0; n < 4; ++n) {
          acc[m][n] = __builtin_amdgcn_mfma_f32_16x16x32_bf16(ah[m], bh[n], acc[m][n], 0, 0, 0);
          acc[m][n] = __builtin_amdgcn_mfma_f32_16x16x32_bf16(ah[m], blo[n], acc[m][n], 0, 0, 0);
          acc[m][n] = __builtin_amdgcn_mfma_f32_16x16x32_bf16(al[m], bh[n], acc[m][n], 0, 0, 0);
        }
    }
  }
  const float* bias = (tau ? bv : bk) + g * DD_;
  float* out = (tau ? Vp : Kp) + (size_t)bl * T_ * DD_;
#pragma unroll
  for (int n = 0; n < 4; ++n) {
    int col = nt * 128 + wn * 64 + n * 16 + (lane & 15);
    float bvv = bias[col];
#pragma unroll
    for (int m = 0; m < 4; ++m) {
      int rbase = mt * 128 + wm * 64 + m * 16 + (lane >> 4) * 4;
#pragma unroll
      for (int q = 0; q < 4; ++q) {
        out[(size_t)(rbase + q) * DD_ + col] = acc[m][n][q] + bvv;
      }
    }
  }
}

// ---------------------------------------------------------------------------
// Attention pooling per (b,l,h): scores -> softmax -> pooled (head_dim-major)
// grid = 72*8 = 576
// ---------------------------------------------------------------------------
__global__ __launch_bounds__(256)
void attn_kernel(const float* __restrict__ Kp, const float* __restrict__ Vp,
                 const float* __restrict__ Qp, float* __restrict__ pooled) {
  int bid = blockIdx.x;
  int h = bid & 7;
  int bl = bid >> 3;
  int tid = threadIdx.x;
  int lane = tid & 63;
  int wv = tid >> 6;
  __shared__ float q_s[64];
  __shared__ float sc[512];
  __shared__ float wred[8];
  __shared__ float pr[4][64];
  if (tid < 64) q_s[tid] = Qp[(size_t)bl * DD_ + h * 64 + tid];
  __syncthreads();
  float qv = q_s[lane];
  const float* Kb = Kp + (size_t)bl * T_ * DD_ + h * 64;
  for (int i0 = wv * 128; i0 < wv * 128 + 128; i0 += 8) {
    float p[8];
#pragma unroll
    for (int j = 0; j < 8; ++j) p[j] = Kb[(size_t)(i0 + j) * DD_ + lane] * qv;
#pragma unroll
    for (int j = 0; j < 8; ++j) {
#pragma unroll
      for (int s = 1; s < 64; s <<= 1) p[j] += __shfl_xor(p[j], s, 64);
      if (lane == j) sc[i0 + j] = p[j] * 0.125f;
    }
  }
  __syncthreads();
  float m = -1e30f;
  for (int i = tid; i < 512; i += 256) m = fmaxf(m, sc[i]);
#pragma unroll
  for (int s = 1; s < 64; s <<= 1) m = fmaxf(m, __shfl_xor(m, s, 64));
  if (lane == 0) wred[wv] = m;
  __syncthreads();
  m = fmaxf(fmaxf(wred[0], wred[1]), fmaxf(wred[2], wred[3]));
  float sum = 0.f;
  for (int i = tid; i < 512; i += 256) {
    float e = __expf(sc[i] - m);
    sc[i] = e;
    sum += e;
  }
#pragma unroll
  for (int s = 1; s < 64; s <<= 1) sum += __shfl_xor(sum, s, 64);
  if (lane == 0) wred[4 + wv] = sum;
  __syncthreads();
  float inv = 1.f / (wred[4] + wred[5] + wred[6] + wred[7]);
  int d = tid & 63, kc = tid >> 6;
  const float* Vb = Vp + (size_t)bl * T_ * DD_ + h * 64;
  float part = 0.f;
  for (int k = kc * 128; k < kc * 128 + 128; k += 4) {
#pragma unroll
    for (int j = 0; j < 4; ++j)
      part = fmaf(sc[k + j], Vb[(size_t)(k + j) * DD_ + d], part);
  }
  pr[kc][d] = part;
  __syncthreads();
  if (tid < 64) {
    float v = (pr[0][tid] + pr[1][tid] + pr[2][tid] + pr[3][tid]) * inv;
    pooled[(size_t)bl * DD_ + tid * 8 + h] = v;  // head_dim-major: d*H + h
  }
}

// ---------------------------------------------------------------------------
// Final mlora: feat[b,l] = pooled @ Wo[g] + bo + LoRA. grid = 72
// ---------------------------------------------------------------------------
__global__ __launch_bounds__(256)
void feat_kernel(const float* __restrict__ pooled, const float* __restrict__ Wo,
                 const float* __restrict__ bo, const float* __restrict__ Ao,
                 const float* __restrict__ Bo, const float* __restrict__ gate,
                 float* __restrict__ out) {
  int bl = blockIdx.x;
  int b = bl / 18, l = bl % 18, g = l / 3;
  int nb = get_nb(gate, b);
  int tid = threadIdx.x;
  __shared__ float x_s[512];
  __shared__ float axp[256][17];
  __shared__ float ax[16];
  const float* x = pooled + (size_t)bl * DD_;
  for (int i = tid; i < 512; i += 256) x_s[i] = x[i];
  const float* A = Ao + ((size_t)(g * 8 + nb) * 16) * DD_;
  __syncthreads();
  float pa[16];
#pragma unroll
  for (int r = 0; r < 16; ++r) pa[r] = 0.f;
  for (int d0 = 0; d0 < 512; d0 += 256) {
    float xv = x_s[d0 + tid];
#pragma unroll
    for (int r = 0; r < 16; ++r) pa[r] = fmaf(xv, A[r * DD_ + d0 + tid], pa[r]);
  }
#pragma unroll
  for (int r = 0; r < 16; ++r) axp[tid][r] = pa[r];
  __syncthreads();
  if (tid < 16) {
    float s = 0.f;
    for (int i = 0; i < 256; ++i) s += axp[i][tid];
    ax[tid] = s;
  }
  __syncthreads();
  const float* W = Wo + (size_t)g * DD_ * OUT_;
  const float* Bm = Bo + (size_t)(g * 8 + nb) * OUT_ * 16;
  float a0 = bo[g * OUT_ + tid];
  float a1 = bo[g * OUT_ + tid + 256];
  float a2 = bo[g * OUT_ + tid + 512];
  float a3 = bo[g * OUT_ + tid + 768];
  for (int d = 0; d < 512; ++d) {
    float xv = x_s[d];
    a0 = fmaf(xv, W[(size_t)d * OUT_ + tid], a0);
    a1 = fmaf(xv, W[(size_t)d * OUT_ + tid + 256], a1);
    a2 = fmaf(xv, W[(size_t)d * OUT_ + tid + 512], a2);
    a3 = fmaf(xv, W[(size_t)d * OUT_ + tid + 768], a3);
  }
#pragma unroll
  for (int r = 0; r < 16; ++r) {
    float av = ax[r];
    a0 = fmaf(av, Bm[tid * 16 + r], a0);
    a1 = fmaf(av, Bm[(tid + 256) * 16 + r], a1);
    a2 = fmaf(av, Bm[(tid + 512) * 16 + r], a2);
    a3 = fmaf(av, Bm[(tid + 768) * 16 + r], a3);
  }
  float* o = out + (size_t)bl * OUT_;
  o[tid] = a0;
  o[tid + 256] = a1;
  o[tid + 512] = a2;
  o[tid + 768] = a3;
}

extern "C" void kernel_launch(void* const* d_in, const int* in_sizes, int n_in,
                              void* d_out, int out_size, void* d_ws, size_t ws_size,
                              hipStream_t stream) {
  const float* K    = (const float*)d_in[0];
  const float* V    = (const float*)d_in[1];
  const float* gate = (const float*)d_in[2];
  const float* qp   = (const float*)d_in[3];
  const float* Wq   = (const float*)d_in[4];
  const float* bq   = (const float*)d_in[5];
  const float* Aq   = (const float*)d_in[6];
  const float* Bq   = (const float*)d_in[7];
  const float* Wk   = (const float*)d_in[8];
  const float* bk   = (const float*)d_in[9];
  const float* Ak   = (const float*)d_in[10];
  const float* Bk   = (const float*)d_in[11];
  const float* Wv   = (const float*)d_in[12];
  const float* bv   = (const float*)d_in[13];
  const float* Av   = (const float*)d_in[14];
  const float* Bv   = (const float*)d_in[15];
  const float* Wo   = (const float*)d_in[16];
  const float* bo   = (const float*)d_in[17];
  const float* Ao   = (const float*)d_in[18];
  const float* Bo   = (const float*)d_in[19];
  float* out = (float*)d_out;
  char* ws = (char*)d_ws;
  unsigned short* weff = (unsigned short*)(ws + WEFF_OFF);
  float* Kp = (float*)(ws + KP_OFF);
  float* Vp = (float*)(ws + VP_OFF);
  float* Qp = (float*)(ws + QP_OFF);
  float* pooled = (float*)(ws + POOL_OFF);

  hipLaunchKernelGGL(build_weff, dim3(6144), dim3(256), 0, stream,
                     Wk, Ak, Bk, Wv, Av, Bv, gate, weff);
  hipLaunchKernelGGL(qp_kernel, dim3(72), dim3(256), 0, stream,
                     qp, Wq, bq, Aq, Bq, gate, Qp);
  hipLaunchKernelGGL(gemm_kv, dim3(2304), dim3(256), 0, stream,
                     K, V, weff, bk, bv, gate, Kp, Vp);
  hipLaunchKernelGGL(attn_kernel, dim3(576), dim3(256), 0, stream,
                     Kp, Vp, Qp, pooled);
  hipLaunchKernelGGL(feat_kernel, dim3(72), dim3(256), 0, stream,
                     pooled, Wo, bo, Ao, Bo, gate, out);
}